// Round 5
// baseline (101.460 us; speedup 1.0000x reference)
//
#include <hip/hip_runtime.h>

#define NN 1024
#define DG 8
#define FO 64
#define FI 128
#define LALPHA 0.2f
#define BR 16        // output rows per fused block
#define SBS 257      // Sb row stride (u32 words): bank = (r + 16u + q) % 32, conflict-free
#define MTS 1032     // Mt row stride (ushorts); 516 words = 4 mod 32 (m97-clean b128 pattern)

typedef __attribute__((ext_vector_type(8))) short bf16x8;
typedef __attribute__((ext_vector_type(4))) float f32x4;

static __device__ __forceinline__ unsigned short f2bf(float x) {
  union { float f; unsigned u; } v; v.f = x;
  unsigned r = v.u + 0x7FFFu + ((v.u >> 16) & 1u);  // round-to-nearest-even
  return (unsigned short)(r >> 16);
}
static __device__ __forceinline__ float bf2f(unsigned short h) {
  union { unsigned u; float f; } v; v.u = ((unsigned)h) << 16;
  return v.f;
}

// ---------------------------------------------------------------------------
// K1 (prep): per block of 16 node-rows:
//  - threads 0..15: dedupe neighbor lists (dups -> -1; .set(1.0) collapses)
//  - all: h = atom@W via bf16 hi/lo MFMA (3 MFMAs ~ fp32), fragments loaded
//    DIRECTLY from global (no LDS staging): A coalesced 32B/lane, W (32 KB,
//    L1/L2-hot) as l16-coalesced scalar loads.
//  - outputs hT[g][f][node] (bf16 transposed), srcv/dstv fp32 (cross-wave
//    reduce via tiny LDS atomics — the only barrier).
// ---------------------------------------------------------------------------
__global__ __launch_bounds__(256) void k_prep(const float* __restrict__ atoms,
                                              const float* __restrict__ W,
                                              const float* __restrict__ a,
                                              const int* __restrict__ edges,
                                              int* __restrict__ uniq,
                                              ushort* __restrict__ hT,
                                              float* __restrict__ srcv,
                                              float* __restrict__ dstv) {
  __shared__ float sp[16], dp[16];
  const int t = threadIdx.x, b = blockIdx.x;
  const int g = b >> 6;            // 64 blocks per graph
  const int rbase = b * 16;        // global row base

  if (t < 16) {
    sp[t] = 0.f; dp[t] = 0.f;
    const int rr = rbase + t;
    int e[DG];
#pragma unroll
    for (int s = 0; s < DG; s++) e[s] = edges[rr * DG + s];
#pragma unroll
    for (int s = 0; s < DG; s++) {
      int v = e[s];
      bool dup = false;
#pragma unroll
      for (int q = 0; q < DG; q++)
        if (q < s && e[q] == v) dup = true;
      uniq[rr * DG + s] = dup ? -1 : v;
    }
  }

  const int w = t >> 6, lane = t & 63, quad = lane >> 4, l16 = lane & 15;
  const float* __restrict__ Ar = atoms + (size_t)(rbase + l16) * FI;
  const float* __restrict__ Wc = W + w * 16 + l16;
  f32x4 acc = {0.f, 0.f, 0.f, 0.f};
#pragma unroll
  for (int kc = 0; kc < 4; kc++) {
    const int k0 = kc * 32 + quad * 8;
    float4 a0 = *(const float4*)(Ar + k0);
    float4 a1 = *(const float4*)(Ar + k0 + 4);
    float av[8] = {a0.x, a0.y, a0.z, a0.w, a1.x, a1.y, a1.z, a1.w};
    float wv[8];
#pragma unroll
    for (int e = 0; e < 8; e++) wv[e] = Wc[(k0 + e) * FO];
    bf16x8 ahi, alo, bhi, blo;
#pragma unroll
    for (int e = 0; e < 8; e++) {
      ushort h = f2bf(av[e]);
      ahi[e] = (short)h;
      alo[e] = (short)f2bf(av[e] - bf2f(h));
      ushort g2 = f2bf(wv[e]);
      bhi[e] = (short)g2;
      blo[e] = (short)f2bf(wv[e] - bf2f(g2));
    }
    acc = __builtin_amdgcn_mfma_f32_16x16x32_bf16(ahi, bhi, acc, 0, 0, 0);
    acc = __builtin_amdgcn_mfma_f32_16x16x32_bf16(ahi, blo, acc, 0, 0, 0);
    acc = __builtin_amdgcn_mfma_f32_16x16x32_bf16(alo, bhi, acc, 0, 0, 0);
  }

  // epilogue: D row m=quad*4+reg (node), col n=l16 (f = w*16+l16)
  const int f = w * 16 + l16;
  const float as_ = a[f], ad_ = a[FO + f];
  float ps[4], pd[4];
#pragma unroll
  for (int r = 0; r < 4; r++) {
    float v = acc[r];
    int rb = rbase + quad * 4 + r;
    hT[((size_t)g * FO + f) * NN + (rb & (NN - 1))] = f2bf(v);
    ps[r] = v * as_;
    pd[r] = v * ad_;
  }
#pragma unroll
  for (int off = 1; off < 16; off <<= 1)
#pragma unroll
    for (int r = 0; r < 4; r++) {
      ps[r] += __shfl_xor(ps[r], off);
      pd[r] += __shfl_xor(pd[r], off);
    }
  __syncthreads();
  if (l16 == 0) {
#pragma unroll
    for (int r = 0; r < 4; r++) {
      atomicAdd(&sp[quad * 4 + r], ps[r]);
      atomicAdd(&dp[quad * 4 + r], pd[r]);
    }
  }
  __syncthreads();
  if (t < 16) {
    srcv[rbase + t] = sp[t];
    dstv[rbase + t] = dp[t];
  }
}

// ---------------------------------------------------------------------------
// K2 (fused): build 16-row blended M strip in LDS, MFMA vs L2-resident hT.
// S counts in u8 byte-lanes of u32 (max count 73 < 255, no carry).
// Mt holds UNSCALED bf16(exp(S)) + att*Z fold; 0.5/Z applied in epilogue:
//   out = elu( (0.5/Z_i) * (exp(S) + att*Z_i) @ h ) = elu(0.5*att@h + 0.5/Z*expS@h)
// 4 barriers/block, single exp pass (64 transcendentals/lane).
// ---------------------------------------------------------------------------
__global__ __launch_bounds__(256) void k_fused(const int* __restrict__ uniq,
                                               const float* __restrict__ srcv,
                                               const float* __restrict__ dstv,
                                               const ushort* __restrict__ hT,
                                               float* __restrict__ out) {
  __shared__ unsigned Sb[BR * SBS];              // 16.4 KB byte counters
  __shared__ __align__(16) ushort Mt[BR * MTS];  // 33 KB bf16 M strip
  __shared__ int n1[BR][DG];
  __shared__ float attw[BR][DG];
  __shared__ float zl[BR][16];
  __shared__ float Zr[BR];

  const int t = threadIdx.x, b = blockIdx.x;
  const int g = b >> 6, rbase = (b & 63) * BR;
  const int* __restrict__ Ug = uniq + (size_t)g * NN * DG;

  for (int i = t; i < BR * SBS; i += 256) Sb[i] = 0u;
  if (t < BR * DG) n1[t >> 3][t & 7] = Ug[(rbase + (t >> 3)) * DG + (t & 7)];
  __syncthreads();

  // level-1 + level-2 scatter (t<128); att softmax (128..143); level-3 (all)
  if (t < 128) {
    int r = t >> 3, s = t & 7;
    int j = n1[r][s];
    if (j >= 0) {
      atomicAdd(&Sb[r * SBS + (j >> 2)], 1u << ((j & 3) * 8));
      int4 k0 = *(const int4*)(Ug + j * DG);
      int4 k1 = *(const int4*)(Ug + j * DG + 4);
      int kk[8] = {k0.x, k0.y, k0.z, k0.w, k1.x, k1.y, k1.z, k1.w};
#pragma unroll
      for (int e = 0; e < 8; e++)
        if (kk[e] >= 0) atomicAdd(&Sb[r * SBS + (kk[e] >> 2)], 1u << ((kk[e] & 3) * 8));
    }
  } else if (t < 128 + BR) {
    int r = t - 128;
    float si = srcv[g * NN + rbase + r];
    float ev[DG];
    float m = -1e30f;
#pragma unroll
    for (int s = 0; s < DG; s++) {
      int j = n1[r][s];
      if (j >= 0) {
        float x = si + dstv[g * NN + j];
        x = x > 0.f ? x : LALPHA * x;
        ev[s] = x;
        m = fmaxf(m, x);
      } else ev[s] = -1e30f;
    }
    float sm = 0.f;
#pragma unroll
    for (int s = 0; s < DG; s++) {
      float e = (n1[r][s] >= 0) ? __expf(ev[s] - m) : 0.f;
      ev[s] = e;
      sm += e;
    }
    float inv = 1.f / sm;
#pragma unroll
    for (int s = 0; s < DG; s++) attw[r][s] = ev[s] * inv;
  }
  // level-3: 1024 (row, pair) items, 4 per thread, y re-derived from L2-hot Ug
#pragma unroll
  for (int q = 0; q < 4; q++) {
    int idx = t + 256 * q;
    int r = idx >> 6, e = idx & 63;
    int j = n1[r][e >> 3];
    if (j >= 0) {
      int k = Ug[j * DG + (e & 7)];
      if (k >= 0) {
        int4 m0 = *(const int4*)(Ug + k * DG);
        int4 m1 = *(const int4*)(Ug + k * DG + 4);
        int ll[8] = {m0.x, m0.y, m0.z, m0.w, m1.x, m1.y, m1.z, m1.w};
#pragma unroll
        for (int e2 = 0; e2 < 8; e2++)
          if (ll[e2] >= 0) atomicAdd(&Sb[r * SBS + (ll[e2] >> 2)], 1u << ((ll[e2] & 3) * 8));
      }
    }
  }
  __syncthreads();

  // single pass: Sb -> Mt (unscaled bf16 exp) + Z partials. r=t&15 bank-clean.
  {
    const int r = t & 15, u = t >> 4;
    float zp = 0.f;
#pragma unroll
    for (int q = 0; q < 8; q++) {
      unsigned s0 = Sb[r * SBS + u * 16 + 2 * q];
      unsigned s1 = Sb[r * SBS + u * 16 + 2 * q + 1];
      float e0 = __expf((float)(s0 & 255u));
      float e1 = __expf((float)((s0 >> 8) & 255u));
      float e2 = __expf((float)((s0 >> 16) & 255u));
      float e3 = __expf((float)(s0 >> 24));
      float e4 = __expf((float)(s1 & 255u));
      float e5 = __expf((float)((s1 >> 8) & 255u));
      float e6 = __expf((float)((s1 >> 16) & 255u));
      float e7 = __expf((float)(s1 >> 24));
      zp += (e0 + e1) + (e2 + e3) + (e4 + e5) + (e6 + e7);
      union { uint4 v; ushort us[8]; } pk;
      pk.us[0] = f2bf(e0); pk.us[1] = f2bf(e1); pk.us[2] = f2bf(e2); pk.us[3] = f2bf(e3);
      pk.us[4] = f2bf(e4); pk.us[5] = f2bf(e5); pk.us[6] = f2bf(e6); pk.us[7] = f2bf(e7);
      *(uint4*)&Mt[r * MTS + u * 64 + q * 8] = pk.v;
    }
    zl[r][u] = zp;
  }
  __syncthreads();

  // att fold-in (Z computed inline from partials; s==0 publishes Zr for epilogue)
  if (t < 128) {
    const int r = t >> 3, s = t & 7;
    float z = 0.f;
#pragma unroll
    for (int u = 0; u < 16; u++) z += zl[r][u];
    if (s == 0) Zr[r] = z;
    int j = n1[r][s];
    if (j >= 0) {
      int adr = r * MTS + j;
      Mt[adr] = f2bf(bf2f(Mt[adr]) + attw[r][s] * z);
    }
  }
  __syncthreads();

  // GEMM: wave w -> out cols w*16..+16; A from LDS Mt, B direct from L2 hT.
  const int w = t >> 6, lane = t & 63, quad = lane >> 4, l16 = lane & 15;
  const ushort* __restrict__ hrow = hT + ((size_t)g * FO + w * 16 + l16) * NN;
  f32x4 acc = {0.f, 0.f, 0.f, 0.f};
#pragma unroll 8
  for (int ks = 0; ks < NN; ks += 32) {
    bf16x8 af = *(const bf16x8*)&Mt[l16 * MTS + ks + quad * 8];
    bf16x8 bf = *(const bf16x8*)(hrow + ks + quad * 8);
    acc = __builtin_amdgcn_mfma_f32_16x16x32_bf16(af, bf, acc, 0, 0, 0);
  }
#pragma unroll
  for (int r = 0; r < 4; r++) {
    int rl = quad * 4 + r;
    float v = acc[r] * (0.5f / Zr[rl]);
    v = v > 0.f ? v : __expf(v) - 1.f;
    out[((size_t)(g * NN + rbase + rl)) * FO + w * 16 + l16] = v;
  }
}

// ---------------------------------------------------------------------------
extern "C" void kernel_launch(void* const* d_in, const int* in_sizes, int n_in,
                              void* d_out, int out_size, void* d_ws, size_t ws_size,
                              hipStream_t stream) {
  const float* atoms = (const float*)d_in[0];
  const int* edges = (const int*)d_in[1];
  const float* W = (const float*)d_in[2];
  const float* a = (const float*)d_in[3];
  float* out = (float*)d_out;

  const int nrows = in_sizes[0] / FI;   // B*N = 16384
  const int ngraph = nrows / NN;        // 16

  ushort* hT = (ushort*)d_ws;                                   // ngraph*FO*NN
  float* srcv = (float*)(hT + (size_t)ngraph * FO * NN);        // nrows
  float* dstv = srcv + nrows;                                   // nrows
  int* uniq = (int*)(dstv + nrows);                             // nrows*DG

  k_prep<<<nrows / 16, 256, 0, stream>>>(atoms, W, a, edges, uniq, hT, srcv, dstv);
  k_fused<<<ngraph * (NN / BR), 256, 0, stream>>>(uniq, srcv, dstv, hT, out);
}